// Round 14
// baseline (184.912 us; speedup 1.0000x reference)
//
#include <hip/hip_runtime.h>

#define NPT 16384
#define MC  512
#define BATCH 8
#define CAP 512
#define LCAP 128

typedef __attribute__((ext_vector_type(8))) __bf16 bf16x8;
typedef __attribute__((ext_vector_type(4))) float f32x4;
typedef __attribute__((ext_vector_type(2))) float f32x2;

static __device__ __forceinline__ unsigned short f2bf(float f) {
    unsigned int u = __float_as_uint(f);
    unsigned int r = (u + 0x7FFFu + ((u >> 16) & 1u)) >> 16;
    return (unsigned short)r;
}

static __device__ __forceinline__ float dist2(float x, float y, float z,
                                              float cx, float cy, float cz) {
    float dx = x - cx, dy = y - cy, dz = z - cz;
    return __fadd_rn(__fadd_rn(__fmul_rn(dx, dx), __fmul_rn(dy, dy)), __fmul_rn(dz, dz));
}

// pair-wise distance, component-explicit _rn ops (identical semantics to dist2; SLP-friendly)
static __device__ __forceinline__ void dist2_pair(f32x2 x, f32x2 y, f32x2 z,
                                                  float cx, float cy, float cz,
                                                  float& d0, float& d1) {
    float dx0 = x[0] - cx, dx1 = x[1] - cx;
    float dy0 = y[0] - cy, dy1 = y[1] - cy;
    float dz0 = z[0] - cz, dz1 = z[1] - cz;
    float a0 = __fmul_rn(dx0, dx0), a1 = __fmul_rn(dx1, dx1);
    float b0 = __fmul_rn(dy0, dy0), b1 = __fmul_rn(dy1, dy1);
    float c0 = __fmul_rn(dz0, dz0), c1 = __fmul_rn(dz1, dz1);
    d0 = __fadd_rn(__fadd_rn(a0, b0), c0);
    d1 = __fadd_rn(__fadd_rn(a1, b1), c1);
}

// ---------------- prep: fold BN into weights (bf16) + SoA transpose + zero counters ----------
// Wp3 is stored PRE-SWIZZLED: Wswz[r][slot s'] = Worig[r][s' ^ (r&7)] (slots = 16B = 8 shorts).
__global__ void prep_all(const float* __restrict__ points,
                         const float* __restrict__ w1, const float* __restrict__ b1,
                         const float* __restrict__ s1, const float* __restrict__ t1,
                         const float* __restrict__ w2, const float* __restrict__ b2,
                         const float* __restrict__ s2, const float* __restrict__ t2,
                         const float* __restrict__ w3, const float* __restrict__ b3,
                         const float* __restrict__ s3, const float* __restrict__ t3,
                         unsigned short* __restrict__ Wp1, unsigned short* __restrict__ Wp2,
                         unsigned short* __restrict__ Wp3,
                         float* __restrict__ bias1, float* __restrict__ bias2,
                         float* __restrict__ bias3, float* __restrict__ soa,
                         int* __restrict__ gcnt) {
    int i = blockIdx.x * blockDim.x + threadIdx.x;
    if (i < 64 * 64) {
        int o = i >> 6;
        Wp1[i] = f2bf(w1[i] * s1[o]);
    } else if (i < 64 * 64 + 128 * 64) {
        int j = i - 4096; int o = j >> 6;
        Wp2[j] = f2bf(w2[j] * s2[o]);
    } else if (i < 64 * 64 + 128 * 64 + 1024 * 128) {
        int j = i - 12288; int o = j >> 7; int col = j & 127;
        int scol = (((col >> 3) ^ (o & 7)) << 3) | (col & 7);
        Wp3[j] = f2bf(w3[(o << 7) | scol] * s3[o]);
    }
    if (i < 64)   bias1[i] = b1[i] * s1[i] + t1[i];
    if (i < 128)  bias2[i] = b2[i] * s2[i] + t2[i];
    if (i < 1024) bias3[i] = b3[i] * s3[i] + t3[i];
    if (i < BATCH * MC) gcnt[i] = 0;
    if (i < BATCH * NPT) {
        int b = i >> 14, j = i & (NPT - 1);
        const float* p = points + ((size_t)b * NPT + j) * 3;
        float* s = soa + (size_t)b * 3 * NPT;
        s[j] = p[0];
        s[NPT + j] = p[1];
        s[2 * NPT + j] = p[2];
    }
}

// ---------------- stage 1: serial scan with cycle detection ----------
__global__ __launch_bounds__(1024) void fps_kernel(const float* __restrict__ pts,
                                                   float* __restrict__ cent) {
    int b = blockIdx.x;
    const float* P = pts + (size_t)b * NPT * 3;
    float* C = cent + (size_t)b * MC * 3;
    __shared__ int hist[MC];
    __shared__ float curx, cury, curz;
    __shared__ float rd[16];
    __shared__ int ri[16];
    __shared__ int s_found, s_j;

    int tid = threadIdx.x;
    int i0 = tid * 16;
    float px[16], py[16], pz[16];
#pragma unroll
    for (int j = 0; j < 16; j++) {
        px[j] = P[(i0 + j) * 3 + 0];
        py[j] = P[(i0 + j) * 3 + 1];
        pz[j] = P[(i0 + j) * 3 + 2];
    }
    if (tid == 0) {
        hist[0] = 0;
        curx = P[0]; cury = P[1]; curz = P[2];
        C[0] = P[0]; C[1] = P[1]; C[2] = P[2];
        s_found = 0; s_j = 0;
    }
    __syncthreads();

    int t;
    for (t = 1; t < MC; t++) {
        float cx = curx, cy = cury, cz = curz;
        float bd = -1.0f; int bi = 0;
#pragma unroll
        for (int j = 0; j < 16; j++) {
            float dx = px[j] - cx, dy = py[j] - cy, dz = pz[j] - cz;
            float d2 = __fadd_rn(__fadd_rn(__fmul_rn(dx, dx), __fmul_rn(dy, dy)), __fmul_rn(dz, dz));
            float d = __fsqrt_rn(d2);
            if (d > bd) { bd = d; bi = i0 + j; }
        }
#pragma unroll
        for (int off = 32; off; off >>= 1) {
            float od = __shfl_xor(bd, off);
            int   oi = __shfl_xor(bi, off);
            if (od > bd || (od == bd && oi < bi)) { bd = od; bi = oi; }
        }
        int wid = tid >> 6;
        if ((tid & 63) == 0) { rd[wid] = bd; ri[wid] = bi; }
        __syncthreads();
        if (tid == 0) {
            float fb = rd[0]; int fi = ri[0];
            for (int wv = 1; wv < 16; wv++)
                if (rd[wv] > fb || (rd[wv] == fb && ri[wv] < fi)) { fb = rd[wv]; fi = ri[wv]; }
            int found = -1;
            for (int j = 0; j < t; j++) if (hist[j] == fi) { found = j; break; }
            hist[t] = fi;
            s_j = found;
            curx = P[fi * 3]; cury = P[fi * 3 + 1]; curz = P[fi * 3 + 2];
            C[t * 3] = curx; C[t * 3 + 1] = cury; C[t * 3 + 2] = curz;
            s_found = (found >= 0);
        }
        __syncthreads();
        if (s_found) break;
    }
    if (s_found && t < MC - 1) {
        int j = s_j, p = t - s_j;
        for (int k = t + 1 + tid; k < MC; k += 1024) {
            int src = j + (k - j) % p;
            int ind = hist[src];
            C[k * 3] = P[ind * 3]; C[k * 3 + 1] = P[ind * 3 + 1]; C[k * 3 + 2] = P[ind * 3 + 2];
        }
    }
}

// ---------------- stage 2a: pair-packed bound + LDS-staged gather ----------
__global__ __launch_bounds__(256) void bound_gather_kernel(
    const float* __restrict__ soa, const float* __restrict__ cent,
    int* __restrict__ gcnt, unsigned long long* __restrict__ gcand) {
    int tid = threadIdx.x, wv = tid >> 6, lane = tid & 63;
    int blk = blockIdx.x;
    int grp = blk >> 2;                  // 0..511
    int chunk = blk & 3;                 // 0..3
    int b = grp >> 6;                    // batch
    int gbase = grp * 8;                 // global centroid base
    const float* Px = soa + (size_t)b * 3 * NPT + chunk * 4096;
    const float* Py = Px + NPT;
    const float* Pz = Py + NPT;

    __shared__ float smin[8][256];             // 8 KB
    __shared__ unsigned int sU[8];
    __shared__ int lcnt[8];
    __shared__ unsigned long long lcand[8][LCAP];  // 8 KB
    __shared__ int gslot[8];

    if (tid < 8) lcnt[tid] = 0;

    float cx[8], cy[8], cz[8];
#pragma unroll
    for (int c = 0; c < 8; c++) {
        cx[c] = __uint_as_float(__builtin_amdgcn_readfirstlane(__float_as_uint(cent[(size_t)(gbase + c) * 3 + 0])));
        cy[c] = __uint_as_float(__builtin_amdgcn_readfirstlane(__float_as_uint(cent[(size_t)(gbase + c) * 3 + 1])));
        cz[c] = __uint_as_float(__builtin_amdgcn_readfirstlane(__float_as_uint(cent[(size_t)(gbase + c) * 3 + 2])));
    }

    float lmin[8];
#pragma unroll
    for (int c = 0; c < 8; c++) lmin[c] = 3.4e38f;
#pragma unroll 2
    for (int k = 0; k < 8; k++) {
        int i = tid * 2 + k * 512;
        f32x2 x = *(const f32x2*)&Px[i];
        f32x2 y = *(const f32x2*)&Py[i];
        f32x2 z = *(const f32x2*)&Pz[i];
#pragma unroll
        for (int c = 0; c < 8; c++) {
            float d0, d1;
            dist2_pair(x, y, z, cx[c], cy[c], cz[c], d0, d1);
            lmin[c] = fminf(lmin[c], fminf(d0, d1));
        }
    }
#pragma unroll
    for (int c = 0; c < 8; c++) smin[c][tid] = lmin[c];
    __syncthreads();

    for (int cc = 0; cc < 2; ++cc) {
        int c = wv * 2 + cc;
        float4 q = *(const float4*)&smin[c][lane << 2];
        float m = fminf(fminf(q.x, q.y), fminf(q.z, q.w));
        unsigned int mb = __float_as_uint(m);
        unsigned int T = 0;
#pragma unroll
        for (int bit = 30; bit >= 0; --bit) {
            unsigned int cnd = T | (1u << bit);
            int cnt = __popcll(__ballot(mb < cnd));
            if (cnt <= 31) T = cnd;       // uniform: s_cselect, no divergence
        }
        float s = __fsqrt_rn(__uint_as_float(T));
        unsigned int u = T;
        for (int it = 0; it < 8 && __fsqrt_rn(__uint_as_float(u + 1u)) <= s; ++it) u++;
        if (lane == 0) sU[c] = u;
    }
    __syncthreads();
    unsigned int U[8];
#pragma unroll
    for (int c = 0; c < 8; c++) U[c] = sU[c];

#pragma unroll 2
    for (int k = 0; k < 8; k++) {
        int i = tid * 2 + k * 512;
        f32x2 x = *(const f32x2*)&Px[i];
        f32x2 y = *(const f32x2*)&Py[i];
        f32x2 z = *(const f32x2*)&Pz[i];
        unsigned int gi = (unsigned int)(chunk * 4096 + i);
#pragma unroll
        for (int c = 0; c < 8; c++) {
            float d0, d1;
            dist2_pair(x, y, z, cx[c], cy[c], cz[c], d0, d1);
            if (__float_as_uint(d0) <= U[c]) {
                int p = atomicAdd(&lcnt[c], 1);
                if (p < LCAP) {
                    unsigned int sb = __float_as_uint(__fsqrt_rn(d0));
                    lcand[c][p] = ((unsigned long long)sb << 32) | gi;
                }
            }
            if (__float_as_uint(d1) <= U[c]) {
                int p = atomicAdd(&lcnt[c], 1);
                if (p < LCAP) {
                    unsigned int sb = __float_as_uint(__fsqrt_rn(d1));
                    lcand[c][p] = ((unsigned long long)sb << 32) | (gi + 1u);
                }
            }
        }
    }
    __syncthreads();

    if (tid < 8) {
        int c = tid, n = lcnt[c];
        int add = (n > LCAP) ? 1000000 : n;
        gslot[c] = atomicAdd(&gcnt[gbase + c], add);
    }
    __syncthreads();
    for (int cc = 0; cc < 2; ++cc) {
        int c = wv * 2 + cc;
        int n = lcnt[c] < LCAP ? lcnt[c] : LCAP;
        int base = gslot[c];
        for (int q = lane; q < n; q += 64) {
            int pos = base + q;
            if (pos < CAP) gcand[(size_t)(gbase + c) * CAP + pos] = lcand[c][q];
        }
    }
}

// ---------------- stage 2b: exact top-32 selection + layer0 (1 centroid per wave) ----------
__global__ __launch_bounds__(256) void select_l0_kernel(
    const float* __restrict__ soa, const float* __restrict__ cent,
    const int* __restrict__ gcnt, const unsigned long long* __restrict__ gcand,
    const float* __restrict__ w0, const float* __restrict__ b0,
    const float* __restrict__ s0, const float* __restrict__ t0,
    unsigned short* __restrict__ h0) {
    int tid = threadIdx.x, wv = tid >> 6, lane = tid & 63;
    int g = blockIdx.x * 4 + wv;          // 0..4095
    int b = g >> 9;
    const float* Px = soa + (size_t)b * 3 * NPT;
    const float* Py = Px + NPT;
    const float* Pz = Py + NPT;

    __shared__ unsigned long long scand[4][CAP];   // 16 KB
    __shared__ float sxyz[4][32][3];

    int n = gcnt[g];
    int nc = n < CAP ? n : CAP;
    for (int q = lane; q < nc; q += 64) scand[wv][q] = gcand[(size_t)g * CAP + q];

    unsigned long long sel = 0, last = 0;
    if (n <= CAP) {
        for (int s = 0; s < 32; s++) {
            unsigned long long best = ~0ull;
            for (int q = lane; q < nc; q += 64) {
                unsigned long long kk = scand[wv][q];
                if ((s == 0 || kk > last) && kk < best) best = kk;
            }
#pragma unroll
            for (int off = 32; off; off >>= 1) {
                unsigned long long o = __shfl_xor(best, off);
                best = o < best ? o : best;
            }
            last = best;
            if (lane == s) sel = best;
        }
    } else {
        for (int s = 0; s < 32; s++) {
            unsigned long long best = ~0ull;
            float ccx = cent[(size_t)g * 3], ccy = cent[(size_t)g * 3 + 1], ccz = cent[(size_t)g * 3 + 2];
            for (int i = lane; i < NPT; i += 64) {
                float d2 = dist2(Px[i], Py[i], Pz[i], ccx, ccy, ccz);
                unsigned int db = __float_as_uint(__fsqrt_rn(d2));
                unsigned long long kk = ((unsigned long long)db << 32) | (unsigned int)i;
                if ((s == 0 || kk > last) && kk < best) best = kk;
            }
#pragma unroll
            for (int off = 32; off; off >>= 1) {
                unsigned long long o = __shfl_xor(best, off);
                best = o < best ? o : best;
            }
            last = best;
            if (lane == s) sel = best;
        }
    }
    if (lane < 32) {
        unsigned int idx = (unsigned int)sel;
        if (idx >= NPT) idx = 0;   // defensive: never fault
        sxyz[wv][lane][0] = Px[idx];
        sxyz[wv][lane][1] = Py[idx];
        sxyz[wv][lane][2] = Pz[idx];
    }

    int o = lane;
    float sw = s0[o];
    float fw0 = w0[o * 3] * sw, fw1 = w0[o * 3 + 1] * sw, fw2 = w0[o * 3 + 2] * sw;
    float fb = b0[o] * sw + t0[o];
    size_t base = ((size_t)g * 32) * 64 + o;
#pragma unroll 8
    for (int r = 0; r < 32; r++) {
        float x = sxyz[wv][r][0], y = sxyz[wv][r][1], z = sxyz[wv][r][2];
        float acc = fmaf(z, fw2, fmaf(y, fw1, fmaf(x, fw0, fb)));
        h0[base + (size_t)r * 64] = f2bf(fmaxf(acc, 0.0f));
    }
}

// ---------------- stages 3-4: W staged in swizzled LDS, 256 rows/block ----------
template <int N>
__global__ __launch_bounds__(256) void gemm_relu_kernel(
    const unsigned short* __restrict__ A, const unsigned short* __restrict__ W,
    const float* __restrict__ bias, unsigned short* __restrict__ Out) {
    __shared__ unsigned short sW[N * 64];
    int tid = threadIdx.x, w = tid >> 6, lane = tid & 63, lr = lane & 15, lq = lane >> 4;
    const int SWEEPS = (N * 64 * 2) / 4096;
#pragma unroll
    for (int sweep = 0; sweep < SWEEPS; ++sweep) {
        int r = sweep * 32 + (tid >> 3), s = tid & 7;
        int ss = s ^ (r & 7);
        *(uint4*)&sW[r * 64 + s * 8] = *(const uint4*)&W[r * 64 + ss * 8];
    }
    __syncthreads();

    int row0 = blockIdx.x * 256 + w * 64;
    const int NT = N / 16;
    f32x4 acc[4][NT];
#pragma unroll
    for (int m = 0; m < 4; m++)
#pragma unroll
        for (int n = 0; n < NT; n++) acc[m][n] = (f32x4){0.f, 0.f, 0.f, 0.f};

    bf16x8 a[4][2];
#pragma unroll
    for (int m = 0; m < 4; m++)
#pragma unroll
        for (int ks = 0; ks < 2; ks++)
            a[m][ks] = *(const bf16x8*)&A[(size_t)(row0 + m * 16 + lr) * 64 + ks * 32 + lq * 8];

#pragma unroll
    for (int ks = 0; ks < 2; ks++)
#pragma unroll
        for (int n = 0; n < NT; n++) {
            bf16x8 wf = *(const bf16x8*)&sW[(n * 16 + lr) * 64 + (((ks * 4 + lq) ^ (lr & 7)) * 8)];
#pragma unroll
            for (int m = 0; m < 4; m++)
                acc[m][n] = __builtin_amdgcn_mfma_f32_16x16x32_bf16(a[m][ks], wf, acc[m][n], 0, 0, 0);
        }

#pragma unroll
    for (int n = 0; n < NT; n++) {
        int col = n * 16 + lr;
        float bb = bias[col];
#pragma unroll
        for (int m = 0; m < 4; m++)
#pragma unroll
            for (int i = 0; i < 4; i++) {
                int rr = row0 + m * 16 + lq * 4 + i;
                Out[(size_t)rr * N + col] = f2bf(fmaxf(acc[m][n][i] + bb, 0.f));
            }
    }
}

// ---------------- stage 5: A in regs; DOUBLE-BUFFERED DMA W-tiles; col-split grid ----------
// Per iteration: issue next tile's global_load_lds FIRST (flight time hides under ~600 cyc of
// ds_read+MFMA+epilogue), compute current buffer, ONE barrier (vmcnt drain is then cheap).
// Buffer safety: DMA targets the buffer whose readers finished at the previous barrier.
// Grid = 1024 row-blocks x 2 col-halves; each block does 4 of the 8 128-col tiles.
__global__ __launch_bounds__(256) void gemm3_max_kernel(
    const unsigned short* __restrict__ A, const unsigned short* __restrict__ W,
    const float* __restrict__ bias, float* __restrict__ Out) {
    __shared__ unsigned short sW[2][128 * 128];   // 2 x 32 KB
    int tid = threadIdx.x, w = tid >> 6, lane = tid & 63, lr = lane & 15, lq = lane >> 4;
    int wr = w >> 1, wc = w & 1;
    int rb = blockIdx.x >> 1, cs = blockIdx.x & 1;
    int row0 = rb * 128 + wr * 64;
    int g0 = row0 >> 5;
    int cb0 = cs * 4;

    bf16x8 a[4][4];
#pragma unroll
    for (int m = 0; m < 4; m++)
#pragma unroll
        for (int ks = 0; ks < 4; ks++)
            a[m][ks] = *(const bf16x8*)&A[(size_t)(row0 + m * 16 + lr) * 128 + ks * 32 + lq * 8];

    // prologue: DMA tile cb0 into buffer 0
#pragma unroll
    for (int j = 0; j < 8; ++j) {
        const unsigned short* g = W + (size_t)cb0 * 16384 + w * 4096 + j * 512 + lane * 8;
        __builtin_amdgcn_global_load_lds(
            (const __attribute__((address_space(1))) void*)g,
            (__attribute__((address_space(3))) void*)&sW[0][w * 4096 + j * 512],
            16, 0, 0);
    }
    __syncthreads();

    for (int t = 0; t < 4; ++t) {
        int cb = cb0 + t;
        int cur = t & 1;
        // issue next tile's DMA into the other buffer (readers done at previous barrier)
        if (t < 3) {
#pragma unroll
            for (int j = 0; j < 8; ++j) {
                const unsigned short* g = W + (size_t)(cb + 1) * 16384 + w * 4096 + j * 512 + lane * 8;
                __builtin_amdgcn_global_load_lds(
                    (const __attribute__((address_space(1))) void*)g,
                    (__attribute__((address_space(3))) void*)&sW[cur ^ 1][w * 4096 + j * 512],
                    16, 0, 0);
            }
        }

        f32x4 acc[4][4];
#pragma unroll
        for (int m = 0; m < 4; m++)
#pragma unroll
            for (int n = 0; n < 4; n++) acc[m][n] = (f32x4){0.f, 0.f, 0.f, 0.f};

#pragma unroll
        for (int ks = 0; ks < 4; ks++)
#pragma unroll
            for (int n = 0; n < 4; n++) {
                int rw = wc * 64 + n * 16 + lr;
                bf16x8 wf = *(const bf16x8*)&sW[cur][rw * 128 + (((ks * 4 + lq) ^ (rw & 7)) * 8)];
#pragma unroll
                for (int m = 0; m < 4; m++)
                    acc[m][n] = __builtin_amdgcn_mfma_f32_16x16x32_bf16(a[m][ks], wf, acc[m][n], 0, 0, 0);
            }

#pragma unroll
        for (int n = 0; n < 4; n++) {
            int col = cb * 128 + wc * 64 + n * 16 + lr;
            float bb = bias[col];
            float v0 = 0.f, v1 = 0.f;
#pragma unroll
            for (int i = 0; i < 4; i++) {
                v0 = fmaxf(v0, fmaxf(acc[0][n][i] + bb, 0.f));
                v0 = fmaxf(v0, fmaxf(acc[1][n][i] + bb, 0.f));
                v1 = fmaxf(v1, fmaxf(acc[2][n][i] + bb, 0.f));
                v1 = fmaxf(v1, fmaxf(acc[3][n][i] + bb, 0.f));
            }
            v0 = fmaxf(v0, __shfl_xor(v0, 16)); v0 = fmaxf(v0, __shfl_xor(v0, 32));
            v1 = fmaxf(v1, __shfl_xor(v1, 16)); v1 = fmaxf(v1, __shfl_xor(v1, 32));
            if (lq == 0) {
                Out[(size_t)g0 * 1024 + col] = v0;
                Out[(size_t)(g0 + 1) * 1024 + col] = v1;
            }
        }
        __syncthreads();   // joins compute on cur AND drains next tile's DMA
    }
}

extern "C" void kernel_launch(void* const* d_in, const int* in_sizes, int n_in,
                              void* d_out, int out_size, void* d_ws, size_t ws_size,
                              hipStream_t stream) {
    const float* points = (const float*)d_in[0];
    const float* w0 = (const float*)d_in[1];
    const float* b0 = (const float*)d_in[2];
    const float* s0 = (const float*)d_in[3];
    const float* t0 = (const float*)d_in[4];
    const float* w1 = (const float*)d_in[5];
    const float* b1 = (const float*)d_in[6];
    const float* s1 = (const float*)d_in[7];
    const float* t1 = (const float*)d_in[8];
    const float* w2 = (const float*)d_in[9];
    const float* b2 = (const float*)d_in[10];
    const float* s2 = (const float*)d_in[11];
    const float* t2 = (const float*)d_in[12];
    const float* w3 = (const float*)d_in[13];
    const float* b3 = (const float*)d_in[14];
    const float* s3 = (const float*)d_in[15];
    const float* t3 = (const float*)d_in[16];

    char* ws = (char*)d_ws;
    float* cent = (float*)(ws + 0);                        // 49152
    unsigned short* Wp1 = (unsigned short*)(ws + 49152);   // 8192
    unsigned short* Wp2 = (unsigned short*)(ws + 57344);   // 16384
    unsigned short* Wp3 = (unsigned short*)(ws + 73728);   // 262144 (pre-swizzled)
    float* bias1 = (float*)(ws + 335872);
    float* bias2 = (float*)(ws + 336128);
    float* bias3 = (float*)(ws + 336640);
    unsigned short* h0 = (unsigned short*)(ws + 340736);   // 16 MB
    unsigned short* h1 = (unsigned short*)(ws + 340736 + 16777216);
    unsigned short* h2 = (unsigned short*)(ws + 340736 + 2 * 16777216);
    int* gcnt = (int*)(ws + 340736 + 3 * 16777216);        // 16 KB
    // aliases with disjoint lifetimes:
    float* soa = (float*)h2;                       // written in prep, read through select_l0 (gemm2 writes h2 later)
    unsigned long long* gcand = (unsigned long long*)h1;  // phase A writes, phase B reads; gemm1 writes h1 after
    float* out = (float*)d_out;

    hipLaunchKernelGGL(prep_all, dim3(560), dim3(256), 0, stream,
                       points, w1, b1, s1, t1, w2, b2, s2, t2, w3, b3, s3, t3,
                       Wp1, Wp2, Wp3, bias1, bias2, bias3, soa, gcnt);
    hipLaunchKernelGGL(fps_kernel, dim3(BATCH), dim3(1024), 0, stream, points, cent);
    hipLaunchKernelGGL(bound_gather_kernel, dim3(2048), dim3(256), 0, stream,
                       soa, cent, gcnt, gcand);
    hipLaunchKernelGGL(select_l0_kernel, dim3(1024), dim3(256), 0, stream,
                       soa, cent, gcnt, gcand, w0, b0, s0, t0, h0);
    hipLaunchKernelGGL((gemm_relu_kernel<64>), dim3(512), dim3(256), 0, stream, h0, Wp1, bias1, h1);
    hipLaunchKernelGGL((gemm_relu_kernel<128>), dim3(512), dim3(256), 0, stream, h1, Wp2, bias2, h2);
    hipLaunchKernelGGL(gemm3_max_kernel, dim3(2048), dim3(256), 0, stream, h2, Wp3, bias3, out);
}

// Round 15
// 169.524 us; speedup vs baseline: 1.0908x; 1.0908x over previous
//
#include <hip/hip_runtime.h>

#define NPT 16384
#define MC  512
#define BATCH 8
#define CAP 512
#define LCAP 128

typedef __attribute__((ext_vector_type(8))) __bf16 bf16x8;
typedef __attribute__((ext_vector_type(4))) float f32x4;
typedef __attribute__((ext_vector_type(16))) float f32x16;
typedef __attribute__((ext_vector_type(2))) float f32x2;

static __device__ __forceinline__ unsigned short f2bf(float f) {
    unsigned int u = __float_as_uint(f);
    unsigned int r = (u + 0x7FFFu + ((u >> 16) & 1u)) >> 16;
    return (unsigned short)r;
}

static __device__ __forceinline__ float dist2(float x, float y, float z,
                                              float cx, float cy, float cz) {
    float dx = x - cx, dy = y - cy, dz = z - cz;
    return __fadd_rn(__fadd_rn(__fmul_rn(dx, dx), __fmul_rn(dy, dy)), __fmul_rn(dz, dz));
}

static __device__ __forceinline__ void dist2_pair(f32x2 x, f32x2 y, f32x2 z,
                                                  float cx, float cy, float cz,
                                                  float& d0, float& d1) {
    float dx0 = x[0] - cx, dx1 = x[1] - cx;
    float dy0 = y[0] - cy, dy1 = y[1] - cy;
    float dz0 = z[0] - cz, dz1 = z[1] - cz;
    float a0 = __fmul_rn(dx0, dx0), a1 = __fmul_rn(dx1, dx1);
    float b0 = __fmul_rn(dy0, dy0), b1 = __fmul_rn(dy1, dy1);
    float c0 = __fmul_rn(dz0, dz0), c1 = __fmul_rn(dz1, dz1);
    d0 = __fadd_rn(__fadd_rn(a0, b0), c0);
    d1 = __fadd_rn(__fadd_rn(a1, b1), c1);
}

// ---------------- prep: fold BN into weights (bf16) + SoA transpose + zero counters ----------
// Wp3 is stored PRE-SWIZZLED: Wswz[r][slot s'] = Worig[r][s' ^ (r&7)] (slots = 16B = 8 shorts).
__global__ void prep_all(const float* __restrict__ points,
                         const float* __restrict__ w1, const float* __restrict__ b1,
                         const float* __restrict__ s1, const float* __restrict__ t1,
                         const float* __restrict__ w2, const float* __restrict__ b2,
                         const float* __restrict__ s2, const float* __restrict__ t2,
                         const float* __restrict__ w3, const float* __restrict__ b3,
                         const float* __restrict__ s3, const float* __restrict__ t3,
                         unsigned short* __restrict__ Wp1, unsigned short* __restrict__ Wp2,
                         unsigned short* __restrict__ Wp3,
                         float* __restrict__ bias1, float* __restrict__ bias2,
                         float* __restrict__ bias3, float* __restrict__ soa,
                         int* __restrict__ gcnt) {
    int i = blockIdx.x * blockDim.x + threadIdx.x;
    if (i < 64 * 64) {
        int o = i >> 6;
        Wp1[i] = f2bf(w1[i] * s1[o]);
    } else if (i < 64 * 64 + 128 * 64) {
        int j = i - 4096; int o = j >> 6;
        Wp2[j] = f2bf(w2[j] * s2[o]);
    } else if (i < 64 * 64 + 128 * 64 + 1024 * 128) {
        int j = i - 12288; int o = j >> 7; int col = j & 127;
        int scol = (((col >> 3) ^ (o & 7)) << 3) | (col & 7);
        Wp3[j] = f2bf(w3[(o << 7) | scol] * s3[o]);
    }
    if (i < 64)   bias1[i] = b1[i] * s1[i] + t1[i];
    if (i < 128)  bias2[i] = b2[i] * s2[i] + t2[i];
    if (i < 1024) bias3[i] = b3[i] * s3[i] + t3[i];
    if (i < BATCH * MC) gcnt[i] = 0;
    if (i < BATCH * NPT) {
        int b = i >> 14, j = i & (NPT - 1);
        const float* p = points + ((size_t)b * NPT + j) * 3;
        float* s = soa + (size_t)b * 3 * NPT;
        s[j] = p[0];
        s[NPT + j] = p[1];
        s[2 * NPT + j] = p[2];
    }
}

// ---------------- stage 1: serial scan with cycle detection ----------
__global__ __launch_bounds__(1024) void fps_kernel(const float* __restrict__ pts,
                                                   float* __restrict__ cent) {
    int b = blockIdx.x;
    const float* P = pts + (size_t)b * NPT * 3;
    float* C = cent + (size_t)b * MC * 3;
    __shared__ int hist[MC];
    __shared__ float curx, cury, curz;
    __shared__ float rd[16];
    __shared__ int ri[16];
    __shared__ int s_found, s_j;

    int tid = threadIdx.x;
    int i0 = tid * 16;
    float px[16], py[16], pz[16];
#pragma unroll
    for (int j = 0; j < 16; j++) {
        px[j] = P[(i0 + j) * 3 + 0];
        py[j] = P[(i0 + j) * 3 + 1];
        pz[j] = P[(i0 + j) * 3 + 2];
    }
    if (tid == 0) {
        hist[0] = 0;
        curx = P[0]; cury = P[1]; curz = P[2];
        C[0] = P[0]; C[1] = P[1]; C[2] = P[2];
        s_found = 0; s_j = 0;
    }
    __syncthreads();

    int t;
    for (t = 1; t < MC; t++) {
        float cx = curx, cy = cury, cz = curz;
        float bd = -1.0f; int bi = 0;
#pragma unroll
        for (int j = 0; j < 16; j++) {
            float dx = px[j] - cx, dy = py[j] - cy, dz = pz[j] - cz;
            float d2 = __fadd_rn(__fadd_rn(__fmul_rn(dx, dx), __fmul_rn(dy, dy)), __fmul_rn(dz, dz));
            float d = __fsqrt_rn(d2);
            if (d > bd) { bd = d; bi = i0 + j; }
        }
#pragma unroll
        for (int off = 32; off; off >>= 1) {
            float od = __shfl_xor(bd, off);
            int   oi = __shfl_xor(bi, off);
            if (od > bd || (od == bd && oi < bi)) { bd = od; bi = oi; }
        }
        int wid = tid >> 6;
        if ((tid & 63) == 0) { rd[wid] = bd; ri[wid] = bi; }
        __syncthreads();
        if (tid == 0) {
            float fb = rd[0]; int fi = ri[0];
            for (int wv = 1; wv < 16; wv++)
                if (rd[wv] > fb || (rd[wv] == fb && ri[wv] < fi)) { fb = rd[wv]; fi = ri[wv]; }
            int found = -1;
            for (int j = 0; j < t; j++) if (hist[j] == fi) { found = j; break; }
            hist[t] = fi;
            s_j = found;
            curx = P[fi * 3]; cury = P[fi * 3 + 1]; curz = P[fi * 3 + 2];
            C[t * 3] = curx; C[t * 3 + 1] = cury; C[t * 3 + 2] = curz;
            s_found = (found >= 0);
        }
        __syncthreads();
        if (s_found) break;
    }
    if (s_found && t < MC - 1) {
        int j = s_j, p = t - s_j;
        for (int k = t + 1 + tid; k < MC; k += 1024) {
            int src = j + (k - j) % p;
            int ind = hist[src];
            C[k * 3] = P[ind * 3]; C[k * 3 + 1] = P[ind * 3 + 1]; C[k * 3 + 2] = P[ind * 3 + 2];
        }
    }
}

// ---------------- stage 2a: pair-packed bound + LDS-staged gather ----------
__global__ __launch_bounds__(256) void bound_gather_kernel(
    const float* __restrict__ soa, const float* __restrict__ cent,
    int* __restrict__ gcnt, unsigned long long* __restrict__ gcand) {
    int tid = threadIdx.x, wv = tid >> 6, lane = tid & 63;
    int blk = blockIdx.x;
    int grp = blk >> 2;                  // 0..511
    int chunk = blk & 3;                 // 0..3
    int b = grp >> 6;                    // batch
    int gbase = grp * 8;                 // global centroid base
    const float* Px = soa + (size_t)b * 3 * NPT + chunk * 4096;
    const float* Py = Px + NPT;
    const float* Pz = Py + NPT;

    __shared__ float smin[8][256];             // 8 KB
    __shared__ unsigned int sU[8];
    __shared__ int lcnt[8];
    __shared__ unsigned long long lcand[8][LCAP];  // 8 KB
    __shared__ int gslot[8];

    if (tid < 8) lcnt[tid] = 0;

    float cx[8], cy[8], cz[8];
#pragma unroll
    for (int c = 0; c < 8; c++) {
        cx[c] = __uint_as_float(__builtin_amdgcn_readfirstlane(__float_as_uint(cent[(size_t)(gbase + c) * 3 + 0])));
        cy[c] = __uint_as_float(__builtin_amdgcn_readfirstlane(__float_as_uint(cent[(size_t)(gbase + c) * 3 + 1])));
        cz[c] = __uint_as_float(__builtin_amdgcn_readfirstlane(__float_as_uint(cent[(size_t)(gbase + c) * 3 + 2])));
    }

    float lmin[8];
#pragma unroll
    for (int c = 0; c < 8; c++) lmin[c] = 3.4e38f;
#pragma unroll 2
    for (int k = 0; k < 8; k++) {
        int i = tid * 2 + k * 512;
        f32x2 x = *(const f32x2*)&Px[i];
        f32x2 y = *(const f32x2*)&Py[i];
        f32x2 z = *(const f32x2*)&Pz[i];
#pragma unroll
        for (int c = 0; c < 8; c++) {
            float d0, d1;
            dist2_pair(x, y, z, cx[c], cy[c], cz[c], d0, d1);
            lmin[c] = fminf(lmin[c], fminf(d0, d1));
        }
    }
#pragma unroll
    for (int c = 0; c < 8; c++) smin[c][tid] = lmin[c];
    __syncthreads();

    for (int cc = 0; cc < 2; ++cc) {
        int c = wv * 2 + cc;
        float4 q = *(const float4*)&smin[c][lane << 2];
        float m = fminf(fminf(q.x, q.y), fminf(q.z, q.w));
        unsigned int mb = __float_as_uint(m);
        unsigned int T = 0;
#pragma unroll
        for (int bit = 30; bit >= 0; --bit) {
            unsigned int cnd = T | (1u << bit);
            int cnt = __popcll(__ballot(mb < cnd));
            if (cnt <= 31) T = cnd;       // uniform: s_cselect, no divergence
        }
        float s = __fsqrt_rn(__uint_as_float(T));
        unsigned int u = T;
        for (int it = 0; it < 8 && __fsqrt_rn(__uint_as_float(u + 1u)) <= s; ++it) u++;
        if (lane == 0) sU[c] = u;
    }
    __syncthreads();
    unsigned int U[8];
#pragma unroll
    for (int c = 0; c < 8; c++) U[c] = sU[c];

#pragma unroll 2
    for (int k = 0; k < 8; k++) {
        int i = tid * 2 + k * 512;
        f32x2 x = *(const f32x2*)&Px[i];
        f32x2 y = *(const f32x2*)&Py[i];
        f32x2 z = *(const f32x2*)&Pz[i];
        unsigned int gi = (unsigned int)(chunk * 4096 + i);
#pragma unroll
        for (int c = 0; c < 8; c++) {
            float d0, d1;
            dist2_pair(x, y, z, cx[c], cy[c], cz[c], d0, d1);
            if (__float_as_uint(d0) <= U[c]) {
                int p = atomicAdd(&lcnt[c], 1);
                if (p < LCAP) {
                    unsigned int sb = __float_as_uint(__fsqrt_rn(d0));
                    lcand[c][p] = ((unsigned long long)sb << 32) | gi;
                }
            }
            if (__float_as_uint(d1) <= U[c]) {
                int p = atomicAdd(&lcnt[c], 1);
                if (p < LCAP) {
                    unsigned int sb = __float_as_uint(__fsqrt_rn(d1));
                    lcand[c][p] = ((unsigned long long)sb << 32) | (gi + 1u);
                }
            }
        }
    }
    __syncthreads();

    if (tid < 8) {
        int c = tid, n = lcnt[c];
        int add = (n > LCAP) ? 1000000 : n;
        gslot[c] = atomicAdd(&gcnt[gbase + c], add);
    }
    __syncthreads();
    for (int cc = 0; cc < 2; ++cc) {
        int c = wv * 2 + cc;
        int n = lcnt[c] < LCAP ? lcnt[c] : LCAP;
        int base = gslot[c];
        for (int q = lane; q < n; q += 64) {
            int pos = base + q;
            if (pos < CAP) gcand[(size_t)(gbase + c) * CAP + pos] = lcand[c][q];
        }
    }
}

// ---------------- stage 2b: exact top-32 selection + layer0 (1 centroid per wave) ----------
__global__ __launch_bounds__(256) void select_l0_kernel(
    const float* __restrict__ soa, const float* __restrict__ cent,
    const int* __restrict__ gcnt, const unsigned long long* __restrict__ gcand,
    const float* __restrict__ w0, const float* __restrict__ b0,
    const float* __restrict__ s0, const float* __restrict__ t0,
    unsigned short* __restrict__ h0) {
    int tid = threadIdx.x, wv = tid >> 6, lane = tid & 63;
    int g = blockIdx.x * 4 + wv;          // 0..4095
    int b = g >> 9;
    const float* Px = soa + (size_t)b * 3 * NPT;
    const float* Py = Px + NPT;
    const float* Pz = Py + NPT;

    __shared__ unsigned long long scand[4][CAP];   // 16 KB
    __shared__ float sxyz[4][32][3];

    int n = gcnt[g];
    int nc = n < CAP ? n : CAP;
    for (int q = lane; q < nc; q += 64) scand[wv][q] = gcand[(size_t)g * CAP + q];

    unsigned long long sel = 0, last = 0;
    if (n <= CAP) {
        for (int s = 0; s < 32; s++) {
            unsigned long long best = ~0ull;
            for (int q = lane; q < nc; q += 64) {
                unsigned long long kk = scand[wv][q];
                if ((s == 0 || kk > last) && kk < best) best = kk;
            }
#pragma unroll
            for (int off = 32; off; off >>= 1) {
                unsigned long long o = __shfl_xor(best, off);
                best = o < best ? o : best;
            }
            last = best;
            if (lane == s) sel = best;
        }
    } else {
        for (int s = 0; s < 32; s++) {
            unsigned long long best = ~0ull;
            float ccx = cent[(size_t)g * 3], ccy = cent[(size_t)g * 3 + 1], ccz = cent[(size_t)g * 3 + 2];
            for (int i = lane; i < NPT; i += 64) {
                float d2 = dist2(Px[i], Py[i], Pz[i], ccx, ccy, ccz);
                unsigned int db = __float_as_uint(__fsqrt_rn(d2));
                unsigned long long kk = ((unsigned long long)db << 32) | (unsigned int)i;
                if ((s == 0 || kk > last) && kk < best) best = kk;
            }
#pragma unroll
            for (int off = 32; off; off >>= 1) {
                unsigned long long o = __shfl_xor(best, off);
                best = o < best ? o : best;
            }
            last = best;
            if (lane == s) sel = best;
        }
    }
    if (lane < 32) {
        unsigned int idx = (unsigned int)sel;
        if (idx >= NPT) idx = 0;   // defensive: never fault
        sxyz[wv][lane][0] = Px[idx];
        sxyz[wv][lane][1] = Py[idx];
        sxyz[wv][lane][2] = Pz[idx];
    }

    int o = lane;
    float sw = s0[o];
    float fw0 = w0[o * 3] * sw, fw1 = w0[o * 3 + 1] * sw, fw2 = w0[o * 3 + 2] * sw;
    float fb = b0[o] * sw + t0[o];
    size_t base = ((size_t)g * 32) * 64 + o;
#pragma unroll 8
    for (int r = 0; r < 32; r++) {
        float x = sxyz[wv][r][0], y = sxyz[wv][r][1], z = sxyz[wv][r][2];
        float acc = fmaf(z, fw2, fmaf(y, fw1, fmaf(x, fw0, fb)));
        h0[base + (size_t)r * 64] = f2bf(fmaxf(acc, 0.0f));
    }
}

// ---------------- stages 3-4: W staged in swizzled LDS, 256 rows/block ----------
template <int N>
__global__ __launch_bounds__(256) void gemm_relu_kernel(
    const unsigned short* __restrict__ A, const unsigned short* __restrict__ W,
    const float* __restrict__ bias, unsigned short* __restrict__ Out) {
    __shared__ unsigned short sW[N * 64];
    int tid = threadIdx.x, w = tid >> 6, lane = tid & 63, lr = lane & 15, lq = lane >> 4;
    const int SWEEPS = (N * 64 * 2) / 4096;
#pragma unroll
    for (int sweep = 0; sweep < SWEEPS; ++sweep) {
        int r = sweep * 32 + (tid >> 3), s = tid & 7;
        int ss = s ^ (r & 7);
        *(uint4*)&sW[r * 64 + s * 8] = *(const uint4*)&W[r * 64 + ss * 8];
    }
    __syncthreads();

    int row0 = blockIdx.x * 256 + w * 64;
    const int NT = N / 16;
    f32x4 acc[4][NT];
#pragma unroll
    for (int m = 0; m < 4; m++)
#pragma unroll
        for (int n = 0; n < NT; n++) acc[m][n] = (f32x4){0.f, 0.f, 0.f, 0.f};

    bf16x8 a[4][2];
#pragma unroll
    for (int m = 0; m < 4; m++)
#pragma unroll
        for (int ks = 0; ks < 2; ks++)
            a[m][ks] = *(const bf16x8*)&A[(size_t)(row0 + m * 16 + lr) * 64 + ks * 32 + lq * 8];

#pragma unroll
    for (int ks = 0; ks < 2; ks++)
#pragma unroll
        for (int n = 0; n < NT; n++) {
            bf16x8 wf = *(const bf16x8*)&sW[(n * 16 + lr) * 64 + (((ks * 4 + lq) ^ (lr & 7)) * 8)];
#pragma unroll
            for (int m = 0; m < 4; m++)
                acc[m][n] = __builtin_amdgcn_mfma_f32_16x16x32_bf16(a[m][ks], wf, acc[m][n], 0, 0, 0);
        }

#pragma unroll
    for (int n = 0; n < NT; n++) {
        int col = n * 16 + lr;
        float bb = bias[col];
#pragma unroll
        for (int m = 0; m < 4; m++)
#pragma unroll
            for (int i = 0; i < 4; i++) {
                int rr = row0 + m * 16 + lq * 4 + i;
                Out[(size_t)rr * N + col] = f2bf(fmaxf(acc[m][n][i] + bb, 0.f));
            }
    }
}

// ---------------- stage 5: 32x32 MFMA, group-aligned max-pool (1 shuffle/output) ----------
// mfma_f32_32x32x16_bf16: C/D col=lane&31, rows {0-3,8-11,16-19,24-27}+4*(lane>>5) — one MFMA
// m-position == one 32-row pooling group; lane holds 16 of its 32 rows, lane^32 the rest.
// Epilogue per (m,n): 15-fmax in-lane tree + 1 shfl_xor(32) + bias + relu (exactly equal to
// per-element bias+relu then max, since +bb and relu are monotone and bb is per-col).
// W pre-swizzled in global; DMA-staged linear; single 32 KB buffer, 2-barrier loop.
__global__ __launch_bounds__(256) void gemm3_max_kernel(
    const unsigned short* __restrict__ A, const unsigned short* __restrict__ W,
    const float* __restrict__ bias, float* __restrict__ Out) {
    __shared__ unsigned short sW[128 * 128];   // 32 KB
    int tid = threadIdx.x, w = tid >> 6, lane = tid & 63;
    int l32 = lane & 31, hi = lane >> 5;
    int wr = w >> 1, wc = w & 1;
    int row0 = blockIdx.x * 128 + wr * 64;
    int g0 = row0 >> 5;                 // first 32-row group of this wave

    // A frags: lane holds A[row0 + m*32 + l32][ks*16 + hi*8 .. +8]  (read from HBM once)
    bf16x8 a[2][8];
#pragma unroll
    for (int m = 0; m < 2; m++)
#pragma unroll
        for (int ks = 0; ks < 8; ks++)
            a[m][ks] = *(const bf16x8*)&A[(size_t)(row0 + m * 32 + l32) * 128 + ks * 16 + hi * 8];

    for (int cb = 0; cb < 8; ++cb) {
        // stage tile cb: 8 DMA instructions per wave, each 64 lanes x 16 B = 1 KB linear
#pragma unroll
        for (int j = 0; j < 8; ++j) {
            const unsigned short* g = W + (size_t)cb * 16384 + w * 4096 + j * 512 + lane * 8;
            __builtin_amdgcn_global_load_lds(
                (const __attribute__((address_space(1))) void*)g,
                (__attribute__((address_space(3))) void*)&sW[w * 4096 + j * 512],
                16, 0, 0);
        }
        __syncthreads();   // drains vmcnt: DMA complete for all waves

        f32x16 acc[2][2];
#pragma unroll
        for (int m = 0; m < 2; m++)
#pragma unroll
            for (int n = 0; n < 2; n++)
#pragma unroll
                for (int r = 0; r < 16; r++) acc[m][n][r] = 0.f;

#pragma unroll
        for (int ks = 0; ks < 8; ks++)
#pragma unroll
            for (int n = 0; n < 2; n++) {
                int rw = wc * 64 + n * 32 + l32;
                int slot = (ks * 2 + hi) ^ (rw & 7);
                bf16x8 wf = *(const bf16x8*)&sW[rw * 128 + slot * 8];
#pragma unroll
                for (int m = 0; m < 2; m++)
                    acc[m][n] = __builtin_amdgcn_mfma_f32_32x32x16_bf16(a[m][ks], wf, acc[m][n], 0, 0, 0);
            }

#pragma unroll
        for (int n = 0; n < 2; n++) {
            int col = cb * 128 + wc * 64 + n * 32 + l32;
            float bb = bias[col];
#pragma unroll
            for (int m = 0; m < 2; m++) {
                // in-lane tree max over this lane's 16 rows of group g0+m
                float t0_ = fmaxf(acc[m][n][0], acc[m][n][1]);
                float t1_ = fmaxf(acc[m][n][2], acc[m][n][3]);
                float t2_ = fmaxf(acc[m][n][4], acc[m][n][5]);
                float t3_ = fmaxf(acc[m][n][6], acc[m][n][7]);
                float t4_ = fmaxf(acc[m][n][8], acc[m][n][9]);
                float t5_ = fmaxf(acc[m][n][10], acc[m][n][11]);
                float t6_ = fmaxf(acc[m][n][12], acc[m][n][13]);
                float t7_ = fmaxf(acc[m][n][14], acc[m][n][15]);
                float u0 = fmaxf(t0_, t1_), u1 = fmaxf(t2_, t3_);
                float u2 = fmaxf(t4_, t5_), u3 = fmaxf(t6_, t7_);
                float v = fmaxf(fmaxf(u0, u1), fmaxf(u2, u3));
                v = fmaxf(v, __shfl_xor(v, 32));   // other 16 rows of the group
                v = fmaxf(v + bb, 0.f);
                if (hi == 0) Out[(size_t)(g0 + m) * 1024 + col] = v;
            }
        }
        __syncthreads();   // all reads done before next tile's DMA overwrites
    }
}

extern "C" void kernel_launch(void* const* d_in, const int* in_sizes, int n_in,
                              void* d_out, int out_size, void* d_ws, size_t ws_size,
                              hipStream_t stream) {
    const float* points = (const float*)d_in[0];
    const float* w0 = (const float*)d_in[1];
    const float* b0 = (const float*)d_in[2];
    const float* s0 = (const float*)d_in[3];
    const float* t0 = (const float*)d_in[4];
    const float* w1 = (const float*)d_in[5];
    const float* b1 = (const float*)d_in[6];
    const float* s1 = (const float*)d_in[7];
    const float* t1 = (const float*)d_in[8];
    const float* w2 = (const float*)d_in[9];
    const float* b2 = (const float*)d_in[10];
    const float* s2 = (const float*)d_in[11];
    const float* t2 = (const float*)d_in[12];
    const float* w3 = (const float*)d_in[13];
    const float* b3 = (const float*)d_in[14];
    const float* s3 = (const float*)d_in[15];
    const float* t3 = (const float*)d_in[16];

    char* ws = (char*)d_ws;
    float* cent = (float*)(ws + 0);                        // 49152
    unsigned short* Wp1 = (unsigned short*)(ws + 49152);   // 8192
    unsigned short* Wp2 = (unsigned short*)(ws + 57344);   // 16384
    unsigned short* Wp3 = (unsigned short*)(ws + 73728);   // 262144 (pre-swizzled)
    float* bias1 = (float*)(ws + 335872);
    float* bias2 = (float*)(ws + 336128);
    float* bias3 = (float*)(ws + 336640);
    unsigned short* h0 = (unsigned short*)(ws + 340736);   // 16 MB
    unsigned short* h1 = (unsigned short*)(ws + 340736 + 16777216);
    unsigned short* h2 = (unsigned short*)(ws + 340736 + 2 * 16777216);
    int* gcnt = (int*)(ws + 340736 + 3 * 16777216);        // 16 KB
    // aliases with disjoint lifetimes:
    float* soa = (float*)h2;                       // written in prep, read through select_l0 (gemm2 writes h2 later)
    unsigned long long* gcand = (unsigned long long*)h1;  // phase A writes, phase B reads; gemm1 writes h1 after
    float* out = (float*)d_out;

    hipLaunchKernelGGL(prep_all, dim3(560), dim3(256), 0, stream,
                       points, w1, b1, s1, t1, w2, b2, s2, t2, w3, b3, s3, t3,
                       Wp1, Wp2, Wp3, bias1, bias2, bias3, soa, gcnt);
    hipLaunchKernelGGL(fps_kernel, dim3(BATCH), dim3(1024), 0, stream, points, cent);
    hipLaunchKernelGGL(bound_gather_kernel, dim3(2048), dim3(256), 0, stream,
                       soa, cent, gcnt, gcand);
    hipLaunchKernelGGL(select_l0_kernel, dim3(1024), dim3(256), 0, stream,
                       soa, cent, gcnt, gcand, w0, b0, s0, t0, h0);
    hipLaunchKernelGGL((gemm_relu_kernel<64>), dim3(512), dim3(256), 0, stream, h0, Wp1, bias1, h1);
    hipLaunchKernelGGL((gemm_relu_kernel<128>), dim3(512), dim3(256), 0, stream, h1, Wp2, bias2, h2);
    hipLaunchKernelGGL(gemm3_max_kernel, dim3(1024), dim3(256), 0, stream, h2, Wp3, bias3, out);
}